// Round 1
// baseline (779.432 us; speedup 1.0000x reference)
//
#include <hip/hip_runtime.h>
#include <hip/hip_bf16.h>
#include <math.h>

#define B_ 4
#define T_ 2048
#define D_ 1024
#define F_ 2048
#define E_ 8
#define NT (B_ * T_)          // 8192 tokens
#define NS (NT * 2)           // 16384 routed assignments (K=2)
#define CAP (NS + E_ * 128)   // 17408 slots: 128-aligned per-expert segments always fit

typedef __attribute__((ext_vector_type(8))) short short8;
typedef __attribute__((ext_vector_type(4))) float floatx4;

static __device__ __forceinline__ unsigned short f2bf(float f) {
  union { float f; unsigned u; } a; a.f = f;
  unsigned r = a.u + 0x7fffu + ((a.u >> 16) & 1u);  // RNE
  return (unsigned short)(r >> 16);
}

static __device__ __forceinline__ void gld16(const unsigned short* g, unsigned short* l) {
  __builtin_amdgcn_global_load_lds(
      (const __attribute__((address_space(1))) void*)g,
      (__attribute__((address_space(3))) void*)l, 16, 0, 0);
}

// ---- weight transpose + fp32->bf16 convert: in [E][R][C] -> out [E][C][R] ----
__global__ void transpose_cvt(const float* __restrict__ in, unsigned short* __restrict__ out,
                              int R, int C) {
  __shared__ float tile[32][33];
  int e = blockIdx.z;
  const float* inp = in + (size_t)e * R * C;
  unsigned short* outp = out + (size_t)e * R * C;
  int c0 = blockIdx.x * 32, r0 = blockIdx.y * 32;
  int tx = threadIdx.x, ty = threadIdx.y;
#pragma unroll
  for (int j = 0; j < 4; j++)
    tile[ty + 8 * j][tx] = inp[(size_t)(r0 + ty + 8 * j) * C + c0 + tx];
  __syncthreads();
#pragma unroll
  for (int j = 0; j < 4; j++)
    outp[(size_t)(c0 + ty + 8 * j) * R + r0 + tx] = f2bf(tile[tx][ty + 8 * j]);
}

// ---- router: fp32 logits, top-2, softmax over the pair ----
__global__ void router_k(const float* __restrict__ x, const float* __restrict__ gw,
                         const float* __restrict__ gb, int* __restrict__ ti,
                         float* __restrict__ tw, int* __restrict__ counts) {
  int wid = threadIdx.x >> 6, lane = threadIdx.x & 63;
  int t = blockIdx.x * 4 + wid;
  const float* xr = x + (size_t)t * D_;
  float acc[E_];
#pragma unroll
  for (int e = 0; e < E_; e++) acc[e] = 0.f;
  for (int d = lane; d < D_; d += 64) {
    float xv = xr[d];
    const float* g = gw + d * E_;
#pragma unroll
    for (int e = 0; e < E_; e++) acc[e] += xv * g[e];
  }
#pragma unroll
  for (int off = 32; off > 0; off >>= 1)
#pragma unroll
    for (int e = 0; e < E_; e++) acc[e] += __shfl_xor(acc[e], off);
  if (lane == 0) {
    float v[E_];
#pragma unroll
    for (int e = 0; e < E_; e++) v[e] = acc[e] + gb[e];
    int i0 = 0; float v0 = v[0];
#pragma unroll
    for (int e = 1; e < E_; e++) if (v[e] > v0) { v0 = v[e]; i0 = e; }
    int i1 = -1; float v1 = -3.4e38f;
#pragma unroll
    for (int e = 0; e < E_; e++) if (e != i0 && v[e] > v1) { v1 = v[e]; i1 = e; }
    float ex = expf(v1 - v0);           // <= 1, no overflow
    float w0 = 1.f / (1.f + ex);
    float w1 = ex / (1.f + ex);
    ti[2 * t] = i0; tw[2 * t] = w0;
    ti[2 * t + 1] = i1; tw[2 * t + 1] = w1;
    atomicAdd(&counts[i0], 1);
    atomicAdd(&counts[i1], 1);
  }
}

// ---- 128-aligned exclusive prefix over 8 counts ----
__global__ void prefix_k(const int* __restrict__ counts, int* __restrict__ offs,
                         int* __restrict__ cursors) {
  if (threadIdx.x == 0 && blockIdx.x == 0) {
    int o = 0;
    for (int e = 0; e < E_; e++) {
      offs[e] = o;
      cursors[e] = o;
      o += (counts[e] + 127) & ~127;
    }
    offs[E_] = o;
  }
}

__global__ void fill_k(int* __restrict__ idx, float* __restrict__ wgt) {
  int s = blockIdx.x * 256 + threadIdx.x;
  if (s < CAP) { idx[s] = 0; wgt[s] = 0.f; }
}

__global__ void scatter_k(const int* __restrict__ ti, const float* __restrict__ tw,
                          int* __restrict__ cursors, int* __restrict__ idx,
                          float* __restrict__ wgt) {
  int a = blockIdx.x * 256 + threadIdx.x;  // 0..NS-1
  int e = ti[a];
  int pos = atomicAdd(&cursors[e], 1);
  idx[pos] = a >> 1;
  wgt[pos] = tw[a];
}

// ---- gather routed token rows into bf16, slot-major ----
__global__ void gather_k(const float* __restrict__ x, const int* __restrict__ idx,
                         unsigned short* __restrict__ Xg) {
  int s = blockIdx.x;
  int t = idx[s];
  const float4* xr = (const float4*)(x + (size_t)t * D_);
  float4 v = xr[threadIdx.x];
  uint2 p;
  p.x = (unsigned)f2bf(v.x) | ((unsigned)f2bf(v.y) << 16);
  p.y = (unsigned)f2bf(v.z) | ((unsigned)f2bf(v.w) << 16);
  ((uint2*)(Xg + (size_t)s * D_))[threadIdx.x] = p;
}

// ---- GEMM1: H = gelu(Xg @ w1[e] + b1[e]), bf16 out. A,B both [rows][K] bf16. ----
__global__ __launch_bounds__(256) void gemm1_k(const unsigned short* __restrict__ Xg,
                                               const unsigned short* __restrict__ w1t,
                                               const float* __restrict__ b1,
                                               unsigned short* __restrict__ H,
                                               const int* __restrict__ offs) {
  int slot0 = blockIdx.y * 128;
  if (slot0 >= offs[E_]) return;
  int e = 0;
  while (slot0 >= offs[e + 1]) e++;
  const int K = D_;
  const unsigned short* Bp = w1t + (size_t)e * F_ * D_;
  int n0 = blockIdx.x * 128;

  __shared__ unsigned short lA[128 * 32];
  __shared__ unsigned short lB[128 * 32];

  int tid = threadIdx.x;
  int wid = tid >> 6, lane = tid & 63;
  int wr = wid >> 1, wc = wid & 1;
  int quad = lane >> 4, l15 = lane & 15;

  int srow = 32 * wid + (lane >> 2);
  int scol = (lane & 3) * 8;
  const unsigned short* gA0 = Xg + (size_t)(slot0 + srow) * K + scol;
  const unsigned short* gA1 = gA0 + (size_t)16 * K;
  const unsigned short* gB0 = Bp + (size_t)(n0 + srow) * K + scol;
  const unsigned short* gB1 = gB0 + (size_t)16 * K;
  unsigned short* lA0 = &lA[(32 * wid) * 32];
  unsigned short* lA1 = &lA[(32 * wid + 16) * 32];
  unsigned short* lB0 = &lB[(32 * wid) * 32];
  unsigned short* lB1 = &lB[(32 * wid + 16) * 32];

  floatx4 acc[4][4];
#pragma unroll
  for (int mi = 0; mi < 4; mi++)
#pragma unroll
    for (int ni = 0; ni < 4; ni++) acc[mi][ni] = (floatx4){0.f, 0.f, 0.f, 0.f};

  for (int k0 = 0; k0 < K; k0 += 32) {
    gld16(gA0 + k0, lA0);
    gld16(gA1 + k0, lA1);
    gld16(gB0 + k0, lB0);
    gld16(gB1 + k0, lB1);
    __syncthreads();
    short8 af[4], bfr[4];
#pragma unroll
    for (int mi = 0; mi < 4; mi++)
      af[mi] = *(const short8*)&lA[(64 * wr + 16 * mi + l15) * 32 + quad * 8];
#pragma unroll
    for (int ni = 0; ni < 4; ni++)
      bfr[ni] = *(const short8*)&lB[(64 * wc + 16 * ni + l15) * 32 + quad * 8];
#pragma unroll
    for (int mi = 0; mi < 4; mi++)
#pragma unroll
      for (int ni = 0; ni < 4; ni++)
        acc[mi][ni] = __builtin_amdgcn_mfma_f32_16x16x32_bf16(af[mi], bfr[ni], acc[mi][ni], 0, 0, 0);
    __syncthreads();
  }

  const float* bias = b1 + (size_t)e * F_;
#pragma unroll
  for (int mi = 0; mi < 4; mi++) {
    int row = slot0 + 64 * wr + 16 * mi + quad * 4;
#pragma unroll
    for (int ni = 0; ni < 4; ni++) {
      int col = n0 + 64 * wc + 16 * ni + l15;
      float bv = bias[col];
#pragma unroll
      for (int r = 0; r < 4; r++) {
        float v = acc[mi][ni][r] + bv;
        v = 0.5f * v * (1.f + erff(v * 0.70710678118654752f));
        H[(size_t)(row + r) * F_ + col] = f2bf(v);
      }
    }
  }
}

// ---- GEMM2: y = H @ w2[e] + b2[e]; out[token] += weight * y (atomic) ----
__global__ __launch_bounds__(256) void gemm2_k(const unsigned short* __restrict__ H,
                                               const unsigned short* __restrict__ w2t,
                                               const float* __restrict__ b2,
                                               const int* __restrict__ idx,
                                               const float* __restrict__ wgt,
                                               float* __restrict__ out,
                                               const int* __restrict__ offs) {
  int slot0 = blockIdx.y * 128;
  if (slot0 >= offs[E_]) return;
  int e = 0;
  while (slot0 >= offs[e + 1]) e++;
  const int K = F_;
  const unsigned short* Bp = w2t + (size_t)e * D_ * F_;
  int n0 = blockIdx.x * 128;

  __shared__ unsigned short lA[128 * 32];
  __shared__ unsigned short lB[128 * 32];

  int tid = threadIdx.x;
  int wid = tid >> 6, lane = tid & 63;
  int wr = wid >> 1, wc = wid & 1;
  int quad = lane >> 4, l15 = lane & 15;

  int srow = 32 * wid + (lane >> 2);
  int scol = (lane & 3) * 8;
  const unsigned short* gA0 = H + (size_t)(slot0 + srow) * K + scol;
  const unsigned short* gA1 = gA0 + (size_t)16 * K;
  const unsigned short* gB0 = Bp + (size_t)(n0 + srow) * K + scol;
  const unsigned short* gB1 = gB0 + (size_t)16 * K;
  unsigned short* lA0 = &lA[(32 * wid) * 32];
  unsigned short* lA1 = &lA[(32 * wid + 16) * 32];
  unsigned short* lB0 = &lB[(32 * wid) * 32];
  unsigned short* lB1 = &lB[(32 * wid + 16) * 32];

  floatx4 acc[4][4];
#pragma unroll
  for (int mi = 0; mi < 4; mi++)
#pragma unroll
    for (int ni = 0; ni < 4; ni++) acc[mi][ni] = (floatx4){0.f, 0.f, 0.f, 0.f};

  for (int k0 = 0; k0 < K; k0 += 32) {
    gld16(gA0 + k0, lA0);
    gld16(gA1 + k0, lA1);
    gld16(gB0 + k0, lB0);
    gld16(gB1 + k0, lB1);
    __syncthreads();
    short8 af[4], bfr[4];
#pragma unroll
    for (int mi = 0; mi < 4; mi++)
      af[mi] = *(const short8*)&lA[(64 * wr + 16 * mi + l15) * 32 + quad * 8];
#pragma unroll
    for (int ni = 0; ni < 4; ni++)
      bfr[ni] = *(const short8*)&lB[(64 * wc + 16 * ni + l15) * 32 + quad * 8];
#pragma unroll
    for (int mi = 0; mi < 4; mi++)
#pragma unroll
      for (int ni = 0; ni < 4; ni++)
        acc[mi][ni] = __builtin_amdgcn_mfma_f32_16x16x32_bf16(af[mi], bfr[ni], acc[mi][ni], 0, 0, 0);
    __syncthreads();
  }

  const float* bias = b2 + (size_t)e * D_;
#pragma unroll
  for (int mi = 0; mi < 4; mi++) {
    int row = slot0 + 64 * wr + 16 * mi + quad * 4;
#pragma unroll
    for (int r = 0; r < 4; r++) {
      int slot = row + r;
      int t = idx[slot];
      float w = wgt[slot];
      if (w != 0.f) {
        float* orow = out + (size_t)t * D_;
#pragma unroll
        for (int ni = 0; ni < 4; ni++) {
          int col = n0 + 64 * wc + 16 * ni + l15;
          float v = acc[mi][ni][r] + bias[col];
          atomicAdd(&orow[col], w * v);
        }
      }
    }
  }
}

extern "C" void kernel_launch(void* const* d_in, const int* in_sizes, int n_in,
                              void* d_out, int out_size, void* d_ws, size_t ws_size,
                              hipStream_t stream) {
  const float* x  = (const float*)d_in[0];
  const float* gw = (const float*)d_in[1];
  const float* gb = (const float*)d_in[2];
  const float* w1 = (const float*)d_in[3];
  const float* b1 = (const float*)d_in[4];
  const float* w2 = (const float*)d_in[5];
  const float* b2 = (const float*)d_in[6];
  float* out = (float*)d_out;

  char* p = (char*)d_ws;
  unsigned short* w1t = (unsigned short*)p; p += (size_t)E_ * D_ * F_ * 2;
  unsigned short* w2t = (unsigned short*)p; p += (size_t)E_ * D_ * F_ * 2;
  unsigned short* Xg  = (unsigned short*)p; p += (size_t)CAP * D_ * 2;
  unsigned short* H   = (unsigned short*)p; p += (size_t)CAP * F_ * 2;
  int*   idx = (int*)p;   p += (size_t)CAP * 4;
  float* wgt = (float*)p; p += (size_t)CAP * 4;
  int*   ti  = (int*)p;   p += (size_t)NS * 4;
  float* tw  = (float*)p; p += (size_t)NS * 4;
  int* counts  = (int*)p; p += 64;
  int* cursors = (int*)p; p += 64;
  int* offs    = (int*)p; p += 64;

  hipMemsetAsync(out, 0, (size_t)NT * D_ * 4, stream);
  hipMemsetAsync(counts, 0, 128, stream);  // counts + cursors

  dim3 tb(32, 8);
  transpose_cvt<<<dim3(F_ / 32, D_ / 32, E_), tb, 0, stream>>>(w1, w1t, D_, F_);
  transpose_cvt<<<dim3(D_ / 32, F_ / 32, E_), tb, 0, stream>>>(w2, w2t, F_, D_);
  router_k<<<NT / 4, 256, 0, stream>>>(x, gw, gb, ti, tw, counts);
  prefix_k<<<1, 64, 0, stream>>>(counts, offs, cursors);
  fill_k<<<(CAP + 255) / 256, 256, 0, stream>>>(idx, wgt);
  scatter_k<<<NS / 256, 256, 0, stream>>>(ti, tw, cursors, idx, wgt);
  gather_k<<<CAP, 256, 0, stream>>>(x, idx, Xg);
  gemm1_k<<<dim3(F_ / 128, CAP / 128), 256, 0, stream>>>(Xg, w1t, b1, H, offs);
  gemm2_k<<<dim3(D_ / 128, CAP / 128), 256, 0, stream>>>(H, w2t, b2, idx, wgt, out, offs);
}

// Round 2
// 558.592 us; speedup vs baseline: 1.3954x; 1.3954x over previous
//
#include <hip/hip_runtime.h>
#include <hip/hip_bf16.h>
#include <math.h>

#define B_ 4
#define T_ 2048
#define D_ 1024
#define F_ 2048
#define E_ 8
#define NT (B_ * T_)          // 8192 tokens
#define NS (NT * 2)           // 16384 routed assignments (K=2)
#define CAP (NS + E_ * 128)   // 17408 slots: 128-aligned per-expert segments always fit

typedef __attribute__((ext_vector_type(8))) short short8;
typedef __attribute__((ext_vector_type(4))) float floatx4;

static __device__ __forceinline__ unsigned short f2bf(float f) {
  union { float f; unsigned u; } a; a.f = f;
  unsigned r = a.u + 0x7fffu + ((a.u >> 16) & 1u);  // RNE
  return (unsigned short)(r >> 16);
}

static __device__ __forceinline__ void gld16(const unsigned short* g, unsigned short* l) {
  __builtin_amdgcn_global_load_lds(
      (const __attribute__((address_space(1))) void*)g,
      (__attribute__((address_space(3))) void*)l, 16, 0, 0);
}

// ---- weight transpose + fp32->bf16 convert: in [E][R][C] -> out [E][C][R] ----
__global__ void transpose_cvt(const float* __restrict__ in, unsigned short* __restrict__ out,
                              int R, int C) {
  __shared__ float tile[32][33];
  int e = blockIdx.z;
  const float* inp = in + (size_t)e * R * C;
  unsigned short* outp = out + (size_t)e * R * C;
  int c0 = blockIdx.x * 32, r0 = blockIdx.y * 32;
  int tx = threadIdx.x, ty = threadIdx.y;
#pragma unroll
  for (int j = 0; j < 4; j++)
    tile[ty + 8 * j][tx] = inp[(size_t)(r0 + ty + 8 * j) * C + c0 + tx];
  __syncthreads();
#pragma unroll
  for (int j = 0; j < 4; j++)
    outp[(size_t)(c0 + ty + 8 * j) * R + r0 + tx] = f2bf(tile[tx][ty + 8 * j]);
}

// ---- router: fp32 logits, top-2, softmax over the pair. NO atomics. ----
__global__ void router_k(const float* __restrict__ x, const float* __restrict__ gw,
                         const float* __restrict__ gb, int* __restrict__ ti,
                         float* __restrict__ tw) {
  int wid = threadIdx.x >> 6, lane = threadIdx.x & 63;
  int t = blockIdx.x * 4 + wid;
  const float* xr = x + (size_t)t * D_;
  float acc[E_];
#pragma unroll
  for (int e = 0; e < E_; e++) acc[e] = 0.f;
#pragma unroll
  for (int it = 0; it < D_ / 64; it++) {
    int d = it * 64 + lane;
    float xv = xr[d];
    const float* g = gw + d * E_;
#pragma unroll
    for (int e = 0; e < E_; e++) acc[e] += xv * g[e];
  }
#pragma unroll
  for (int off = 32; off > 0; off >>= 1)
#pragma unroll
    for (int e = 0; e < E_; e++) acc[e] += __shfl_xor(acc[e], off);
  if (lane == 0) {
    float v[E_];
#pragma unroll
    for (int e = 0; e < E_; e++) v[e] = acc[e] + gb[e];
    int i0 = 0; float v0 = v[0];
#pragma unroll
    for (int e = 1; e < E_; e++) if (v[e] > v0) { v0 = v[e]; i0 = e; }
    int i1 = -1; float v1 = -3.4e38f;
#pragma unroll
    for (int e = 0; e < E_; e++) if (e != i0 && v[e] > v1) { v1 = v[e]; i1 = e; }
    float ex = expf(v1 - v0);           // <= 1, no overflow
    float w0 = 1.f / (1.f + ex);
    float w1 = ex / (1.f + ex);
    ti[2 * t] = i0; tw[2 * t] = w0;
    ti[2 * t + 1] = i1; tw[2 * t + 1] = w1;
  }
}

// ---- single-block histogram + 128-aligned exclusive prefix ----
__global__ void count_prefix_k(const int* __restrict__ ti, int* __restrict__ offs,
                               int* __restrict__ cursors) {
  __shared__ int scnt[4][E_];
  int tid = threadIdx.x;  // 256 threads
  int cnt[E_];
#pragma unroll
  for (int k = 0; k < E_; k++) cnt[k] = 0;
  for (int i = tid; i < NS; i += 256) {
    int e = ti[i];
#pragma unroll
    for (int k = 0; k < E_; k++) cnt[k] += (e == k) ? 1 : 0;
  }
#pragma unroll
  for (int off = 32; off > 0; off >>= 1)
#pragma unroll
    for (int k = 0; k < E_; k++) cnt[k] += __shfl_xor(cnt[k], off);
  int wid = tid >> 6, lane = tid & 63;
  if (lane == 0)
#pragma unroll
    for (int k = 0; k < E_; k++) scnt[wid][k] = cnt[k];
  __syncthreads();
  if (tid == 0) {
    int o = 0;
    for (int k = 0; k < E_; k++) {
      int c = scnt[0][k] + scnt[1][k] + scnt[2][k] + scnt[3][k];
      offs[k] = o;
      cursors[k] = o;
      o += (c + 127) & ~127;
    }
    offs[E_] = o;
  }
}

__global__ void fill_k(int* __restrict__ idx, float* __restrict__ wgt) {
  int s = blockIdx.x * 256 + threadIdx.x;
  if (s < CAP) { idx[s] = 0; wgt[s] = 0.f; }
}

// ---- wave-aggregated scatter: 8 atomics per wave instead of 64 ----
__global__ void scatter_k(const int* __restrict__ ti, const float* __restrict__ tw,
                          int* __restrict__ cursors, int* __restrict__ idx,
                          float* __restrict__ wgt) {
  int a = blockIdx.x * 256 + threadIdx.x;  // 0..NS-1
  int lane = threadIdx.x & 63;
  int e = ti[a];
  unsigned long long m[E_];
#pragma unroll
  for (int k = 0; k < E_; k++) m[k] = __ballot(e == k);
  int base = 0;
  if (lane < E_) base = atomicAdd(&cursors[lane], __popcll(m[lane]));
  int myBase = __shfl(base, e);
  unsigned long long m_mine = 0;
#pragma unroll
  for (int k = 0; k < E_; k++) if (e == k) m_mine = m[k];
  int rank = __popcll(m_mine & ((1ull << lane) - 1ull));
  int pos = myBase + rank;
  idx[pos] = a >> 1;
  wgt[pos] = tw[a];
}

// ---- gather routed token rows into bf16, slot-major ----
__global__ void gather_k(const float* __restrict__ x, const int* __restrict__ idx,
                         unsigned short* __restrict__ Xg) {
  int s = blockIdx.x;
  int t = idx[s];
  const float4* xr = (const float4*)(x + (size_t)t * D_);
  float4 v = xr[threadIdx.x];
  uint2 p;
  p.x = (unsigned)f2bf(v.x) | ((unsigned)f2bf(v.y) << 16);
  p.y = (unsigned)f2bf(v.z) | ((unsigned)f2bf(v.w) << 16);
  ((uint2*)(Xg + (size_t)s * D_))[threadIdx.x] = p;
}

// ---- GEMM1: H = gelu(Xg @ w1[e] + b1[e]), bf16 out. A,B both [rows][K] bf16. ----
__global__ __launch_bounds__(256) void gemm1_k(const unsigned short* __restrict__ Xg,
                                               const unsigned short* __restrict__ w1t,
                                               const float* __restrict__ b1,
                                               unsigned short* __restrict__ H,
                                               const int* __restrict__ offs) {
  int slot0 = blockIdx.y * 128;
  if (slot0 >= offs[E_]) return;
  int e = 0;
  while (slot0 >= offs[e + 1]) e++;
  const int K = D_;
  const unsigned short* Bp = w1t + (size_t)e * F_ * D_;
  int n0 = blockIdx.x * 128;

  __shared__ unsigned short lA[128 * 32];
  __shared__ unsigned short lB[128 * 32];

  int tid = threadIdx.x;
  int wid = tid >> 6, lane = tid & 63;
  int wr = wid >> 1, wc = wid & 1;
  int quad = lane >> 4, l15 = lane & 15;

  int srow = 32 * wid + (lane >> 2);
  int scol = (lane & 3) * 8;
  const unsigned short* gA0 = Xg + (size_t)(slot0 + srow) * K + scol;
  const unsigned short* gA1 = gA0 + (size_t)16 * K;
  const unsigned short* gB0 = Bp + (size_t)(n0 + srow) * K + scol;
  const unsigned short* gB1 = gB0 + (size_t)16 * K;
  unsigned short* lA0 = &lA[(32 * wid) * 32];
  unsigned short* lA1 = &lA[(32 * wid + 16) * 32];
  unsigned short* lB0 = &lB[(32 * wid) * 32];
  unsigned short* lB1 = &lB[(32 * wid + 16) * 32];

  floatx4 acc[4][4];
#pragma unroll
  for (int mi = 0; mi < 4; mi++)
#pragma unroll
    for (int ni = 0; ni < 4; ni++) acc[mi][ni] = (floatx4){0.f, 0.f, 0.f, 0.f};

  for (int k0 = 0; k0 < K; k0 += 32) {
    gld16(gA0 + k0, lA0);
    gld16(gA1 + k0, lA1);
    gld16(gB0 + k0, lB0);
    gld16(gB1 + k0, lB1);
    __syncthreads();
    short8 af[4], bfr[4];
#pragma unroll
    for (int mi = 0; mi < 4; mi++)
      af[mi] = *(const short8*)&lA[(64 * wr + 16 * mi + l15) * 32 + quad * 8];
#pragma unroll
    for (int ni = 0; ni < 4; ni++)
      bfr[ni] = *(const short8*)&lB[(64 * wc + 16 * ni + l15) * 32 + quad * 8];
#pragma unroll
    for (int mi = 0; mi < 4; mi++)
#pragma unroll
      for (int ni = 0; ni < 4; ni++)
        acc[mi][ni] = __builtin_amdgcn_mfma_f32_16x16x32_bf16(af[mi], bfr[ni], acc[mi][ni], 0, 0, 0);
    __syncthreads();
  }

  const float* bias = b1 + (size_t)e * F_;
#pragma unroll
  for (int mi = 0; mi < 4; mi++) {
    int row = slot0 + 64 * wr + 16 * mi + quad * 4;
#pragma unroll
    for (int ni = 0; ni < 4; ni++) {
      int col = n0 + 64 * wc + 16 * ni + l15;
      float bv = bias[col];
#pragma unroll
      for (int r = 0; r < 4; r++) {
        float v = acc[mi][ni][r] + bv;
        v = 0.5f * v * (1.f + erff(v * 0.70710678118654752f));
        H[(size_t)(row + r) * F_ + col] = f2bf(v);
      }
    }
  }
}

// ---- GEMM2: y = H @ w2[e] + b2[e]; out[token] += weight * y (atomic) ----
__global__ __launch_bounds__(256) void gemm2_k(const unsigned short* __restrict__ H,
                                               const unsigned short* __restrict__ w2t,
                                               const float* __restrict__ b2,
                                               const int* __restrict__ idx,
                                               const float* __restrict__ wgt,
                                               float* __restrict__ out,
                                               const int* __restrict__ offs) {
  int slot0 = blockIdx.y * 128;
  if (slot0 >= offs[E_]) return;
  int e = 0;
  while (slot0 >= offs[e + 1]) e++;
  const int K = F_;
  const unsigned short* Bp = w2t + (size_t)e * D_ * F_;
  int n0 = blockIdx.x * 128;

  __shared__ unsigned short lA[128 * 32];
  __shared__ unsigned short lB[128 * 32];

  int tid = threadIdx.x;
  int wid = tid >> 6, lane = tid & 63;
  int wr = wid >> 1, wc = wid & 1;
  int quad = lane >> 4, l15 = lane & 15;

  int srow = 32 * wid + (lane >> 2);
  int scol = (lane & 3) * 8;
  const unsigned short* gA0 = H + (size_t)(slot0 + srow) * K + scol;
  const unsigned short* gA1 = gA0 + (size_t)16 * K;
  const unsigned short* gB0 = Bp + (size_t)(n0 + srow) * K + scol;
  const unsigned short* gB1 = gB0 + (size_t)16 * K;
  unsigned short* lA0 = &lA[(32 * wid) * 32];
  unsigned short* lA1 = &lA[(32 * wid + 16) * 32];
  unsigned short* lB0 = &lB[(32 * wid) * 32];
  unsigned short* lB1 = &lB[(32 * wid + 16) * 32];

  floatx4 acc[4][4];
#pragma unroll
  for (int mi = 0; mi < 4; mi++)
#pragma unroll
    for (int ni = 0; ni < 4; ni++) acc[mi][ni] = (floatx4){0.f, 0.f, 0.f, 0.f};

  for (int k0 = 0; k0 < K; k0 += 32) {
    gld16(gA0 + k0, lA0);
    gld16(gA1 + k0, lA1);
    gld16(gB0 + k0, lB0);
    gld16(gB1 + k0, lB1);
    __syncthreads();
    short8 af[4], bfr[4];
#pragma unroll
    for (int mi = 0; mi < 4; mi++)
      af[mi] = *(const short8*)&lA[(64 * wr + 16 * mi + l15) * 32 + quad * 8];
#pragma unroll
    for (int ni = 0; ni < 4; ni++)
      bfr[ni] = *(const short8*)&lB[(64 * wc + 16 * ni + l15) * 32 + quad * 8];
#pragma unroll
    for (int mi = 0; mi < 4; mi++)
#pragma unroll
      for (int ni = 0; ni < 4; ni++)
        acc[mi][ni] = __builtin_amdgcn_mfma_f32_16x16x32_bf16(af[mi], bfr[ni], acc[mi][ni], 0, 0, 0);
    __syncthreads();
  }

  const float* bias = b2 + (size_t)e * D_;
#pragma unroll
  for (int mi = 0; mi < 4; mi++) {
    int row = slot0 + 64 * wr + 16 * mi + quad * 4;
#pragma unroll
    for (int r = 0; r < 4; r++) {
      int slot = row + r;
      int t = idx[slot];
      float w = wgt[slot];
      if (w != 0.f) {
        float* orow = out + (size_t)t * D_;
#pragma unroll
        for (int ni = 0; ni < 4; ni++) {
          int col = n0 + 64 * wc + 16 * ni + l15;
          float v = acc[mi][ni][r] + bias[col];
          atomicAdd(&orow[col], w * v);
        }
      }
    }
  }
}

extern "C" void kernel_launch(void* const* d_in, const int* in_sizes, int n_in,
                              void* d_out, int out_size, void* d_ws, size_t ws_size,
                              hipStream_t stream) {
  const float* x  = (const float*)d_in[0];
  const float* gw = (const float*)d_in[1];
  const float* gb = (const float*)d_in[2];
  const float* w1 = (const float*)d_in[3];
  const float* b1 = (const float*)d_in[4];
  const float* w2 = (const float*)d_in[5];
  const float* b2 = (const float*)d_in[6];
  float* out = (float*)d_out;

  char* p = (char*)d_ws;
  unsigned short* w1t = (unsigned short*)p; p += (size_t)E_ * D_ * F_ * 2;
  unsigned short* w2t = (unsigned short*)p; p += (size_t)E_ * D_ * F_ * 2;
  unsigned short* Xg  = (unsigned short*)p; p += (size_t)CAP * D_ * 2;
  unsigned short* H   = (unsigned short*)p; p += (size_t)CAP * F_ * 2;
  int*   idx = (int*)p;   p += (size_t)CAP * 4;
  float* wgt = (float*)p; p += (size_t)CAP * 4;
  int*   ti  = (int*)p;   p += (size_t)NS * 4;
  float* tw  = (float*)p; p += (size_t)NS * 4;
  int* cursors = (int*)p; p += 64;
  int* offs    = (int*)p; p += 64;

  hipMemsetAsync(out, 0, (size_t)NT * D_ * 4, stream);

  dim3 tb(32, 8);
  transpose_cvt<<<dim3(F_ / 32, D_ / 32, E_), tb, 0, stream>>>(w1, w1t, D_, F_);
  transpose_cvt<<<dim3(D_ / 32, F_ / 32, E_), tb, 0, stream>>>(w2, w2t, F_, D_);
  router_k<<<NT / 4, 256, 0, stream>>>(x, gw, gb, ti, tw);
  count_prefix_k<<<1, 256, 0, stream>>>(ti, offs, cursors);
  fill_k<<<(CAP + 255) / 256, 256, 0, stream>>>(idx, wgt);
  scatter_k<<<NS / 256, 256, 0, stream>>>(ti, tw, cursors, idx, wgt);
  gather_k<<<CAP, 256, 0, stream>>>(x, idx, Xg);
  gemm1_k<<<dim3(F_ / 128, CAP / 128), 256, 0, stream>>>(Xg, w1t, b1, H, offs);
  gemm2_k<<<dim3(D_ / 128, CAP / 128), 256, 0, stream>>>(H, w2t, b2, idx, wgt, out, offs);
}

// Round 3
// 479.119 us; speedup vs baseline: 1.6268x; 1.1659x over previous
//
#include <hip/hip_runtime.h>
#include <hip/hip_bf16.h>
#include <math.h>

#define B_ 4
#define T_ 2048
#define D_ 1024
#define F_ 2048
#define E_ 8
#define NT (B_ * T_)          // 8192 tokens
#define NS (NT * 2)           // 16384 routed assignments (K=2)
#define CAP (NS + E_ * 128)   // 17408 slots: 128-aligned per-expert segments always fit

typedef __attribute__((ext_vector_type(8))) short short8;
typedef __attribute__((ext_vector_type(4))) float floatx4;

static __device__ __forceinline__ unsigned short f2bf(float f) {
  union { float f; unsigned u; } a; a.f = f;
  unsigned r = a.u + 0x7fffu + ((a.u >> 16) & 1u);  // RNE
  return (unsigned short)(r >> 16);
}

static __device__ __forceinline__ float bf2f(unsigned u) {
  union { unsigned u; float f; } a; a.u = u << 16; return a.f;
}

static __device__ __forceinline__ void gld16(const unsigned short* g, unsigned short* l) {
  __builtin_amdgcn_global_load_lds(
      (const __attribute__((address_space(1))) void*)g,
      (__attribute__((address_space(3))) void*)l, 16, 0, 0);
}

// ---- weight transpose + fp32->bf16 convert: in [E][R][C] -> out [E][C][R] ----
__global__ void transpose_cvt(const float* __restrict__ in, unsigned short* __restrict__ out,
                              int R, int C) {
  __shared__ float tile[32][33];
  int e = blockIdx.z;
  const float* inp = in + (size_t)e * R * C;
  unsigned short* outp = out + (size_t)e * R * C;
  int c0 = blockIdx.x * 32, r0 = blockIdx.y * 32;
  int tx = threadIdx.x, ty = threadIdx.y;
#pragma unroll
  for (int j = 0; j < 4; j++)
    tile[ty + 8 * j][tx] = inp[(size_t)(r0 + ty + 8 * j) * C + c0 + tx];
  __syncthreads();
#pragma unroll
  for (int j = 0; j < 4; j++)
    outp[(size_t)(c0 + ty + 8 * j) * R + r0 + tx] = f2bf(tile[tx][ty + 8 * j]);
}

// ---- router: fp32 logits, top-2, softmax over the pair. NO atomics. ----
__global__ void router_k(const float* __restrict__ x, const float* __restrict__ gw,
                         const float* __restrict__ gb, int* __restrict__ ti,
                         float* __restrict__ tw) {
  int wid = threadIdx.x >> 6, lane = threadIdx.x & 63;
  int t = blockIdx.x * 4 + wid;
  const float* xr = x + (size_t)t * D_;
  float acc[E_];
#pragma unroll
  for (int e = 0; e < E_; e++) acc[e] = 0.f;
#pragma unroll
  for (int it = 0; it < D_ / 64; it++) {
    int d = it * 64 + lane;
    float xv = xr[d];
    const float* g = gw + d * E_;
#pragma unroll
    for (int e = 0; e < E_; e++) acc[e] += xv * g[e];
  }
#pragma unroll
  for (int off = 32; off > 0; off >>= 1)
#pragma unroll
    for (int e = 0; e < E_; e++) acc[e] += __shfl_xor(acc[e], off);
  if (lane == 0) {
    float v[E_];
#pragma unroll
    for (int e = 0; e < E_; e++) v[e] = acc[e] + gb[e];
    int i0 = 0; float v0 = v[0];
#pragma unroll
    for (int e = 1; e < E_; e++) if (v[e] > v0) { v0 = v[e]; i0 = e; }
    int i1 = -1; float v1 = -3.4e38f;
#pragma unroll
    for (int e = 0; e < E_; e++) if (e != i0 && v[e] > v1) { v1 = v[e]; i1 = e; }
    float ex = expf(v1 - v0);           // <= 1, no overflow
    float w0 = 1.f / (1.f + ex);
    float w1 = ex / (1.f + ex);
    ti[2 * t] = i0; tw[2 * t] = w0;
    ti[2 * t + 1] = i1; tw[2 * t + 1] = w1;
  }
}

// ---- single-block histogram + 128-aligned exclusive prefix ----
__global__ void count_prefix_k(const int* __restrict__ ti, int* __restrict__ offs,
                               int* __restrict__ cursors) {
  __shared__ int scnt[4][E_];
  int tid = threadIdx.x;  // 256 threads
  int cnt[E_];
#pragma unroll
  for (int k = 0; k < E_; k++) cnt[k] = 0;
  for (int i = tid; i < NS; i += 256) {
    int e = ti[i];
#pragma unroll
    for (int k = 0; k < E_; k++) cnt[k] += (e == k) ? 1 : 0;
  }
#pragma unroll
  for (int off = 32; off > 0; off >>= 1)
#pragma unroll
    for (int k = 0; k < E_; k++) cnt[k] += __shfl_xor(cnt[k], off);
  int wid = tid >> 6, lane = tid & 63;
  if (lane == 0)
#pragma unroll
    for (int k = 0; k < E_; k++) scnt[wid][k] = cnt[k];
  __syncthreads();
  if (tid == 0) {
    int o = 0;
    for (int k = 0; k < E_; k++) {
      int c = scnt[0][k] + scnt[1][k] + scnt[2][k] + scnt[3][k];
      offs[k] = o;
      cursors[k] = o;
      o += (c + 127) & ~127;
    }
    offs[E_] = o;
  }
}

__global__ void fill_k(int* __restrict__ idx) {
  int s = blockIdx.x * 256 + threadIdx.x;
  if (s < CAP) idx[s] = 0;
}

// ---- wave-aggregated scatter: 8 atomics per wave; records slot of each assignment ----
__global__ void scatter_k(const int* __restrict__ ti, const float* __restrict__ tw,
                          int* __restrict__ cursors, int* __restrict__ idx,
                          int* __restrict__ pos_of) {
  int a = blockIdx.x * 256 + threadIdx.x;  // 0..NS-1
  int lane = threadIdx.x & 63;
  int e = ti[a];
  unsigned long long m[E_];
#pragma unroll
  for (int k = 0; k < E_; k++) m[k] = __ballot(e == k);
  int base = 0;
  if (lane < E_) base = atomicAdd(&cursors[lane], __popcll(m[lane]));
  int myBase = __shfl(base, e);
  unsigned long long m_mine = 0;
#pragma unroll
  for (int k = 0; k < E_; k++) if (e == k) m_mine = m[k];
  int rank = __popcll(m_mine & ((1ull << lane) - 1ull));
  int pos = myBase + rank;
  idx[pos] = a >> 1;
  pos_of[a] = pos;
}

// ---- gather routed token rows into bf16, slot-major ----
__global__ void gather_k(const float* __restrict__ x, const int* __restrict__ idx,
                         unsigned short* __restrict__ Xg) {
  int s = blockIdx.x;
  int t = idx[s];
  const float4* xr = (const float4*)(x + (size_t)t * D_);
  float4 v = xr[threadIdx.x];
  uint2 p;
  p.x = (unsigned)f2bf(v.x) | ((unsigned)f2bf(v.y) << 16);
  p.y = (unsigned)f2bf(v.z) | ((unsigned)f2bf(v.w) << 16);
  ((uint2*)(Xg + (size_t)s * D_))[threadIdx.x] = p;
}

// LDS tile layout (both GEMMs): 128 rows x 32 shorts, stored as 4 chunks of 8
// shorts per row, with chunk index XOR-swizzled by (row>>1)&3 so a wave's
// ds_read_b128 pattern covers all 8 bank-groups (2-way residual = free).
// Writer (global_load_lds lane i -> lds base + i*16): stages global chunk
// (i&3)^((i>>3)&3). Reader at row R fetches physical chunk quad^((R>>1)&3).

// ---- GEMM1: H = gelu(Xg @ w1[e] + b1[e]), bf16 out. A,B both [rows][K] bf16. ----
__global__ __launch_bounds__(256) void gemm1_k(const unsigned short* __restrict__ Xg,
                                               const unsigned short* __restrict__ w1t,
                                               const float* __restrict__ b1,
                                               unsigned short* __restrict__ H,
                                               const int* __restrict__ offs) {
  int slot0 = blockIdx.y * 128;
  if (slot0 >= offs[E_]) return;
  int e = 0;
  while (slot0 >= offs[e + 1]) e++;
  const int K = D_;
  const unsigned short* Bp = w1t + (size_t)e * F_ * D_;
  int n0 = blockIdx.x * 128;

  __shared__ unsigned short lA[128 * 32];
  __shared__ unsigned short lB[128 * 32];

  int tid = threadIdx.x;
  int wid = tid >> 6, lane = tid & 63;
  int wr = wid >> 1, wc = wid & 1;
  int quad = lane >> 4, l15 = lane & 15;
  int sw = (l15 >> 1) & 3;  // reader swizzle

  int srow = 32 * wid + (lane >> 2);
  int scol = (((lane & 3) ^ ((lane >> 3) & 3))) * 8;  // writer swizzle
  const unsigned short* gA0 = Xg + (size_t)(slot0 + srow) * K + scol;
  const unsigned short* gA1 = gA0 + (size_t)16 * K;
  const unsigned short* gB0 = Bp + (size_t)(n0 + srow) * K + scol;
  const unsigned short* gB1 = gB0 + (size_t)16 * K;
  unsigned short* lA0 = &lA[(32 * wid) * 32];
  unsigned short* lA1 = &lA[(32 * wid + 16) * 32];
  unsigned short* lB0 = &lB[(32 * wid) * 32];
  unsigned short* lB1 = &lB[(32 * wid + 16) * 32];

  floatx4 acc[4][4];
#pragma unroll
  for (int mi = 0; mi < 4; mi++)
#pragma unroll
    for (int ni = 0; ni < 4; ni++) acc[mi][ni] = (floatx4){0.f, 0.f, 0.f, 0.f};

  for (int k0 = 0; k0 < K; k0 += 32) {
    gld16(gA0 + k0, lA0);
    gld16(gA1 + k0, lA1);
    gld16(gB0 + k0, lB0);
    gld16(gB1 + k0, lB1);
    __syncthreads();
    short8 af[4], bfr[4];
#pragma unroll
    for (int mi = 0; mi < 4; mi++)
      af[mi] = *(const short8*)&lA[(64 * wr + 16 * mi + l15) * 32 + (quad ^ sw) * 8];
#pragma unroll
    for (int ni = 0; ni < 4; ni++)
      bfr[ni] = *(const short8*)&lB[(64 * wc + 16 * ni + l15) * 32 + (quad ^ sw) * 8];
#pragma unroll
    for (int mi = 0; mi < 4; mi++)
#pragma unroll
      for (int ni = 0; ni < 4; ni++)
        acc[mi][ni] = __builtin_amdgcn_mfma_f32_16x16x32_bf16(af[mi], bfr[ni], acc[mi][ni], 0, 0, 0);
    __syncthreads();
  }

  const float* bias = b1 + (size_t)e * F_;
#pragma unroll
  for (int mi = 0; mi < 4; mi++) {
    int row = slot0 + 64 * wr + 16 * mi + quad * 4;
#pragma unroll
    for (int ni = 0; ni < 4; ni++) {
      int col = n0 + 64 * wc + 16 * ni + l15;
      float bv = bias[col];
#pragma unroll
      for (int r = 0; r < 4; r++) {
        float v = acc[mi][ni][r] + bv;
        v = 0.5f * v * (1.f + erff(v * 0.70710678118654752f));
        H[(size_t)(row + r) * F_ + col] = f2bf(v);
      }
    }
  }
}

// ---- GEMM2: Yg[slot] = H @ w2[e] + b2[e], bf16 out. No atomics. ----
__global__ __launch_bounds__(256) void gemm2_k(const unsigned short* __restrict__ H,
                                               const unsigned short* __restrict__ w2t,
                                               const float* __restrict__ b2,
                                               unsigned short* __restrict__ Yg,
                                               const int* __restrict__ offs) {
  int slot0 = blockIdx.y * 128;
  if (slot0 >= offs[E_]) return;
  int e = 0;
  while (slot0 >= offs[e + 1]) e++;
  const int K = F_;
  const unsigned short* Bp = w2t + (size_t)e * D_ * F_;
  int n0 = blockIdx.x * 128;

  __shared__ unsigned short lA[128 * 32];
  __shared__ unsigned short lB[128 * 32];

  int tid = threadIdx.x;
  int wid = tid >> 6, lane = tid & 63;
  int wr = wid >> 1, wc = wid & 1;
  int quad = lane >> 4, l15 = lane & 15;
  int sw = (l15 >> 1) & 3;

  int srow = 32 * wid + (lane >> 2);
  int scol = (((lane & 3) ^ ((lane >> 3) & 3))) * 8;
  const unsigned short* gA0 = H + (size_t)(slot0 + srow) * K + scol;
  const unsigned short* gA1 = gA0 + (size_t)16 * K;
  const unsigned short* gB0 = Bp + (size_t)(n0 + srow) * K + scol;
  const unsigned short* gB1 = gB0 + (size_t)16 * K;
  unsigned short* lA0 = &lA[(32 * wid) * 32];
  unsigned short* lA1 = &lA[(32 * wid + 16) * 32];
  unsigned short* lB0 = &lB[(32 * wid) * 32];
  unsigned short* lB1 = &lB[(32 * wid + 16) * 32];

  floatx4 acc[4][4];
#pragma unroll
  for (int mi = 0; mi < 4; mi++)
#pragma unroll
    for (int ni = 0; ni < 4; ni++) acc[mi][ni] = (floatx4){0.f, 0.f, 0.f, 0.f};

  for (int k0 = 0; k0 < K; k0 += 32) {
    gld16(gA0 + k0, lA0);
    gld16(gA1 + k0, lA1);
    gld16(gB0 + k0, lB0);
    gld16(gB1 + k0, lB1);
    __syncthreads();
    short8 af[4], bfr[4];
#pragma unroll
    for (int mi = 0; mi < 4; mi++)
      af[mi] = *(const short8*)&lA[(64 * wr + 16 * mi + l15) * 32 + (quad ^ sw) * 8];
#pragma unroll
    for (int ni = 0; ni < 4; ni++)
      bfr[ni] = *(const short8*)&lB[(64 * wc + 16 * ni + l15) * 32 + (quad ^ sw) * 8];
#pragma unroll
    for (int mi = 0; mi < 4; mi++)
#pragma unroll
      for (int ni = 0; ni < 4; ni++)
        acc[mi][ni] = __builtin_amdgcn_mfma_f32_16x16x32_bf16(af[mi], bfr[ni], acc[mi][ni], 0, 0, 0);
    __syncthreads();
  }

  const float* bias = b2 + (size_t)e * D_;
#pragma unroll
  for (int mi = 0; mi < 4; mi++) {
    int row = slot0 + 64 * wr + 16 * mi + quad * 4;
#pragma unroll
    for (int ni = 0; ni < 4; ni++) {
      int col = n0 + 64 * wc + 16 * ni + l15;
      float bv = bias[col];
#pragma unroll
      for (int r = 0; r < 4; r++) {
        float v = acc[mi][ni][r] + bv;
        Yg[(size_t)(row + r) * D_ + col] = f2bf(v);
      }
    }
  }
}

// ---- combine: out[t] = w0*Yg[pos(2t)] + w1*Yg[pos(2t+1)] ----
__global__ void combine_k(const unsigned short* __restrict__ Yg,
                          const int* __restrict__ pos_of,
                          const float* __restrict__ tw, float* __restrict__ out) {
  int t = blockIdx.x;
  int p0 = pos_of[2 * t], p1 = pos_of[2 * t + 1];
  float w0 = tw[2 * t], w1 = tw[2 * t + 1];
  uint2 a = ((const uint2*)(Yg + (size_t)p0 * D_))[threadIdx.x];
  uint2 b = ((const uint2*)(Yg + (size_t)p1 * D_))[threadIdx.x];
  float4 r;
  r.x = w0 * bf2f(a.x & 0xffffu) + w1 * bf2f(b.x & 0xffffu);
  r.y = w0 * bf2f(a.x >> 16)     + w1 * bf2f(b.x >> 16);
  r.z = w0 * bf2f(a.y & 0xffffu) + w1 * bf2f(b.y & 0xffffu);
  r.w = w0 * bf2f(a.y >> 16)     + w1 * bf2f(b.y >> 16);
  ((float4*)(out + (size_t)t * D_))[threadIdx.x] = r;
}

extern "C" void kernel_launch(void* const* d_in, const int* in_sizes, int n_in,
                              void* d_out, int out_size, void* d_ws, size_t ws_size,
                              hipStream_t stream) {
  const float* x  = (const float*)d_in[0];
  const float* gw = (const float*)d_in[1];
  const float* gb = (const float*)d_in[2];
  const float* w1 = (const float*)d_in[3];
  const float* b1 = (const float*)d_in[4];
  const float* w2 = (const float*)d_in[5];
  const float* b2 = (const float*)d_in[6];
  float* out = (float*)d_out;

  char* p = (char*)d_ws;
  unsigned short* w1t = (unsigned short*)p; p += (size_t)E_ * D_ * F_ * 2;
  unsigned short* w2t = (unsigned short*)p; p += (size_t)E_ * D_ * F_ * 2;
  unsigned short* Xg  = (unsigned short*)p; p += (size_t)CAP * D_ * 2;
  unsigned short* H   = (unsigned short*)p; p += (size_t)CAP * F_ * 2;
  int*   idx    = (int*)p; p += (size_t)CAP * 4;
  int*   pos_of = (int*)p; p += (size_t)NS * 4;
  int*   ti     = (int*)p; p += (size_t)NS * 4;
  float* tw     = (float*)p; p += (size_t)NS * 4;
  int* cursors = (int*)p; p += 64;
  int* offs    = (int*)p; p += 64;
  unsigned short* Yg = Xg;  // alias: Xg dead after gemm1, Yg born in gemm2

  dim3 tb(32, 8);
  transpose_cvt<<<dim3(F_ / 32, D_ / 32, E_), tb, 0, stream>>>(w1, w1t, D_, F_);
  transpose_cvt<<<dim3(D_ / 32, F_ / 32, E_), tb, 0, stream>>>(w2, w2t, F_, D_);
  router_k<<<NT / 4, 256, 0, stream>>>(x, gw, gb, ti, tw);
  count_prefix_k<<<1, 256, 0, stream>>>(ti, offs, cursors);
  fill_k<<<(CAP + 255) / 256, 256, 0, stream>>>(idx);
  scatter_k<<<NS / 256, 256, 0, stream>>>(ti, tw, cursors, idx, pos_of);
  gather_k<<<CAP, 256, 0, stream>>>(x, idx, Xg);
  gemm1_k<<<dim3(F_ / 128, CAP / 128), 256, 0, stream>>>(Xg, w1t, b1, H, offs);
  gemm2_k<<<dim3(D_ / 128, CAP / 128), 256, 0, stream>>>(H, w2t, b2, Yg, offs);
  combine_k<<<NT, 256, 0, stream>>>(Yg, pos_of, tw, out);
}

// Round 5
// 476.094 us; speedup vs baseline: 1.6371x; 1.0064x over previous
//
#include <hip/hip_runtime.h>
#include <hip/hip_bf16.h>
#include <math.h>

#define B_ 4
#define T_ 2048
#define D_ 1024
#define F_ 2048
#define E_ 8
#define NT (B_ * T_)          // 8192 tokens
#define NS (NT * 2)           // 16384 routed assignments (K=2)
#define CAP (NS + E_ * 128)   // 17408 slots: 128-aligned per-expert segments always fit

typedef __attribute__((ext_vector_type(8))) short short8;
typedef __attribute__((ext_vector_type(4))) float floatx4;

static __device__ __forceinline__ unsigned short f2bf(float f) {
  union { float f; unsigned u; } a; a.f = f;
  unsigned r = a.u + 0x7fffu + ((a.u >> 16) & 1u);  // RNE
  return (unsigned short)(r >> 16);
}

static __device__ __forceinline__ float bf2f(unsigned u) {
  union { unsigned u; float f; } a; a.u = u << 16; return a.f;
}

static __device__ __forceinline__ void gld16(const unsigned short* g, unsigned short* l) {
  __builtin_amdgcn_global_load_lds(
      (const __attribute__((address_space(1))) void*)g,
      (__attribute__((address_space(3))) void*)l, 16, 0, 0);
}

// Branchless GELU: Abramowitz-Stegun 7.1.26 erf (|err| < 1.5e-7), hw exp2/rcp.
static __device__ __forceinline__ float gelu_f(float v) {
  float ax = fabsf(v) * 0.70710678118654752f;
  float t = __builtin_amdgcn_rcpf(1.f + 0.3275911f * ax);
  float e = __builtin_amdgcn_exp2f(-ax * ax * 1.44269504088896f);  // exp(-ax^2)
  float p = t * (0.254829592f +
            t * (-0.284496736f +
            t * (1.421413741f +
            t * (-1.453152027f +
            t * 1.061405429f))));
  float er = 1.f - p * e;
  er = copysignf(er, v);
  return 0.5f * v * (1.f + er);
}

// ---- weight transpose + fp32->bf16 convert: in [E][R][C] -> out [E][C][R] ----
__global__ void transpose_cvt(const float* __restrict__ in, unsigned short* __restrict__ out,
                              int R, int C) {
  __shared__ float tile[32][33];
  int e = blockIdx.z;
  const float* inp = in + (size_t)e * R * C;
  unsigned short* outp = out + (size_t)e * R * C;
  int c0 = blockIdx.x * 32, r0 = blockIdx.y * 32;
  int tx = threadIdx.x, ty = threadIdx.y;
#pragma unroll
  for (int j = 0; j < 4; j++)
    tile[ty + 8 * j][tx] = inp[(size_t)(r0 + ty + 8 * j) * C + c0 + tx];
  __syncthreads();
#pragma unroll
  for (int j = 0; j < 4; j++)
    outp[(size_t)(c0 + ty + 8 * j) * R + r0 + tx] = f2bf(tile[tx][ty + 8 * j]);
}

// ---- router: fp32 logits, top-2, softmax over the pair. NO atomics. ----
__global__ void router_k(const float* __restrict__ x, const float* __restrict__ gw,
                         const float* __restrict__ gb, int* __restrict__ ti,
                         float* __restrict__ tw) {
  int wid = threadIdx.x >> 6, lane = threadIdx.x & 63;
  int t = blockIdx.x * 4 + wid;
  const float* xr = x + (size_t)t * D_;
  float acc[E_];
#pragma unroll
  for (int e = 0; e < E_; e++) acc[e] = 0.f;
#pragma unroll
  for (int it = 0; it < D_ / 64; it++) {
    int d = it * 64 + lane;
    float xv = xr[d];
    const float* g = gw + d * E_;
#pragma unroll
    for (int e = 0; e < E_; e++) acc[e] += xv * g[e];
  }
#pragma unroll
  for (int off = 32; off > 0; off >>= 1)
#pragma unroll
    for (int e = 0; e < E_; e++) acc[e] += __shfl_xor(acc[e], off);
  if (lane == 0) {
    float v[E_];
#pragma unroll
    for (int e = 0; e < E_; e++) v[e] = acc[e] + gb[e];
    int i0 = 0; float v0 = v[0];
#pragma unroll
    for (int e = 1; e < E_; e++) if (v[e] > v0) { v0 = v[e]; i0 = e; }
    int i1 = -1; float v1 = -3.4e38f;
#pragma unroll
    for (int e = 0; e < E_; e++) if (e != i0 && v[e] > v1) { v1 = v[e]; i1 = e; }
    float ex = expf(v1 - v0);           // <= 1, no overflow
    float w0 = 1.f / (1.f + ex);
    float w1 = ex / (1.f + ex);
    ti[2 * t] = i0; tw[2 * t] = w0;
    ti[2 * t + 1] = i1; tw[2 * t + 1] = w1;
  }
}

// ---- single-block histogram + 128-aligned exclusive prefix ----
__global__ void count_prefix_k(const int* __restrict__ ti, int* __restrict__ offs,
                               int* __restrict__ cursors) {
  __shared__ int scnt[4][E_];
  int tid = threadIdx.x;  // 256 threads
  int cnt[E_];
#pragma unroll
  for (int k = 0; k < E_; k++) cnt[k] = 0;
  for (int i = tid; i < NS; i += 256) {
    int e = ti[i];
#pragma unroll
    for (int k = 0; k < E_; k++) cnt[k] += (e == k) ? 1 : 0;
  }
#pragma unroll
  for (int off = 32; off > 0; off >>= 1)
#pragma unroll
    for (int k = 0; k < E_; k++) cnt[k] += __shfl_xor(cnt[k], off);
  int wid = tid >> 6, lane = tid & 63;
  if (lane == 0)
#pragma unroll
    for (int k = 0; k < E_; k++) scnt[wid][k] = cnt[k];
  __syncthreads();
  if (tid == 0) {
    int o = 0;
    for (int k = 0; k < E_; k++) {
      int c = scnt[0][k] + scnt[1][k] + scnt[2][k] + scnt[3][k];
      offs[k] = o;
      cursors[k] = o;
      o += (c + 127) & ~127;
    }
    offs[E_] = o;
  }
}

__global__ void fill_k(int* __restrict__ idx) {
  int s = blockIdx.x * 256 + threadIdx.x;
  if (s < CAP) idx[s] = 0;
}

// ---- wave-aggregated scatter: 8 atomics per wave; records slot of each assignment ----
__global__ void scatter_k(const int* __restrict__ ti, const float* __restrict__ tw,
                          int* __restrict__ cursors, int* __restrict__ idx,
                          int* __restrict__ pos_of) {
  int a = blockIdx.x * 256 + threadIdx.x;  // 0..NS-1
  int lane = threadIdx.x & 63;
  int e = ti[a];
  unsigned long long m[E_];
#pragma unroll
  for (int k = 0; k < E_; k++) m[k] = __ballot(e == k);
  int base = 0;
  if (lane < E_) base = atomicAdd(&cursors[lane], __popcll(m[lane]));
  int myBase = __shfl(base, e);
  unsigned long long m_mine = 0;
#pragma unroll
  for (int k = 0; k < E_; k++) if (e == k) m_mine = m[k];
  int rank = __popcll(m_mine & ((1ull << lane) - 1ull));
  int pos = myBase + rank;
  idx[pos] = a >> 1;
  pos_of[a] = pos;
}

// ---- gather routed token rows into bf16, slot-major ----
__global__ void gather_k(const float* __restrict__ x, const int* __restrict__ idx,
                         unsigned short* __restrict__ Xg) {
  int s = blockIdx.x;
  int t = idx[s];
  const float4* xr = (const float4*)(x + (size_t)t * D_);
  float4 v = xr[threadIdx.x];
  uint2 p;
  p.x = (unsigned)f2bf(v.x) | ((unsigned)f2bf(v.y) << 16);
  p.y = (unsigned)f2bf(v.z) | ((unsigned)f2bf(v.w) << 16);
  ((uint2*)(Xg + (size_t)s * D_))[threadIdx.x] = p;
}

// ---- grouped GEMM, BK=64, 128x128 tile, 4 waves x 4x4 mfma_16x16x32_bf16 ----
// LDS tile: 128 rows x 64 shorts (8 chunks of 8 shorts/row). XOR swizzle:
// writer (gld16 lane i): stages global chunk (i&7)^(i>>3) of row 8j+(i>>3);
// reader row R, k-sub 'sub', quad q: physical chunk ((sub<<2)|q)^(R&7).
// 16 lanes/phase cover all 32 banks 2-way (free). Coalescing: 8 lanes/row
// cover a permuted contiguous 128B span.
template <int K, int N, bool GELU>
__global__ __launch_bounds__(256) void gemm_k(const unsigned short* __restrict__ A,
                                              const unsigned short* __restrict__ W,
                                              const float* __restrict__ bias_all,
                                              unsigned short* __restrict__ O,
                                              const int* __restrict__ offs) {
  int slot0 = blockIdx.y * 128;
  if (slot0 >= offs[E_]) return;
  int e = 0;
  while (slot0 >= offs[e + 1]) e++;
  const unsigned short* Bp = W + (size_t)e * N * K;
  int n0 = blockIdx.x * 128;

  __shared__ unsigned short lA[128 * 64];
  __shared__ unsigned short lB[128 * 64];

  int tid = threadIdx.x;
  int wid = tid >> 6, lane = tid & 63;
  int wr = wid >> 1, wc = wid & 1;
  int quad = lane >> 4, l15 = lane & 15;
  int l7 = l15 & 7;

  // staging addresses
  int sr = lane >> 3;                  // 0..7
  int ch = (lane & 7) ^ sr;            // swizzled chunk
  const unsigned short* gA = A + (size_t)(slot0 + 32 * wid + sr) * K + ch * 8;
  const unsigned short* gB = Bp + (size_t)(n0 + 32 * wid + sr) * K + ch * 8;

  floatx4 acc[4][4];
#pragma unroll
  for (int mi = 0; mi < 4; mi++)
#pragma unroll
    for (int ni = 0; ni < 4; ni++) acc[mi][ni] = (floatx4){0.f, 0.f, 0.f, 0.f};

  for (int k0 = 0; k0 < K; k0 += 64) {
#pragma unroll
    for (int j = 0; j < 4; j++) {
      gld16(gA + k0 + (size_t)8 * j * K, &lA[(32 * wid + 8 * j) * 64]);
      gld16(gB + k0 + (size_t)8 * j * K, &lB[(32 * wid + 8 * j) * 64]);
    }
    __syncthreads();
#pragma unroll
    for (int sub = 0; sub < 2; sub++) {
      short8 af[4], bfr[4];
#pragma unroll
      for (int mi = 0; mi < 4; mi++) {
        int row = 64 * wr + 16 * mi + l15;
        af[mi] = *(const short8*)&lA[row * 64 + ((((sub << 2) | quad)) ^ l7) * 8];
      }
#pragma unroll
      for (int ni = 0; ni < 4; ni++) {
        int row = 64 * wc + 16 * ni + l15;
        bfr[ni] = *(const short8*)&lB[row * 64 + ((((sub << 2) | quad)) ^ l7) * 8];
      }
#pragma unroll
      for (int mi = 0; mi < 4; mi++)
#pragma unroll
        for (int ni = 0; ni < 4; ni++)
          acc[mi][ni] = __builtin_amdgcn_mfma_f32_16x16x32_bf16(af[mi], bfr[ni], acc[mi][ni], 0, 0, 0);
    }
    __syncthreads();
  }

  const float* bias = bias_all + (size_t)e * N;
#pragma unroll
  for (int mi = 0; mi < 4; mi++) {
    int row = slot0 + 64 * wr + 16 * mi + quad * 4;
#pragma unroll
    for (int ni = 0; ni < 4; ni++) {
      int col = n0 + 64 * wc + 16 * ni + l15;
      float bv = bias[col];
#pragma unroll
      for (int r = 0; r < 4; r++) {
        float v = acc[mi][ni][r] + bv;
        if (GELU) v = gelu_f(v);
        O[(size_t)(row + r) * N + col] = f2bf(v);
      }
    }
  }
}

// ---- combine: out[t] = w0*Yg[pos(2t)] + w1*Yg[pos(2t+1)] ----
__global__ void combine_k(const unsigned short* __restrict__ Yg,
                          const int* __restrict__ pos_of,
                          const float* __restrict__ tw, float* __restrict__ out) {
  int t = blockIdx.x;
  int p0 = pos_of[2 * t], p1 = pos_of[2 * t + 1];
  float w0 = tw[2 * t], w1 = tw[2 * t + 1];
  uint2 a = ((const uint2*)(Yg + (size_t)p0 * D_))[threadIdx.x];
  uint2 b = ((const uint2*)(Yg + (size_t)p1 * D_))[threadIdx.x];
  float4 r;
  r.x = w0 * bf2f(a.x & 0xffffu) + w1 * bf2f(b.x & 0xffffu);
  r.y = w0 * bf2f(a.x >> 16)     + w1 * bf2f(b.x >> 16);
  r.z = w0 * bf2f(a.y & 0xffffu) + w1 * bf2f(b.y & 0xffffu);
  r.w = w0 * bf2f(a.y >> 16)     + w1 * bf2f(b.y >> 16);
  ((float4*)(out + (size_t)t * D_))[threadIdx.x] = r;
}

extern "C" void kernel_launch(void* const* d_in, const int* in_sizes, int n_in,
                              void* d_out, int out_size, void* d_ws, size_t ws_size,
                              hipStream_t stream) {
  const float* x  = (const float*)d_in[0];
  const float* gw = (const float*)d_in[1];
  const float* gb = (const float*)d_in[2];
  const float* w1 = (const float*)d_in[3];
  const float* b1 = (const float*)d_in[4];
  const float* w2 = (const float*)d_in[5];
  const float* b2 = (const float*)d_in[6];
  float* out = (float*)d_out;

  char* p = (char*)d_ws;
  unsigned short* w1t = (unsigned short*)p; p += (size_t)E_ * D_ * F_ * 2;
  unsigned short* w2t = (unsigned short*)p; p += (size_t)E_ * D_ * F_ * 2;
  unsigned short* Xg  = (unsigned short*)p; p += (size_t)CAP * D_ * 2;
  unsigned short* H   = (unsigned short*)p; p += (size_t)CAP * F_ * 2;
  int*   idx    = (int*)p; p += (size_t)CAP * 4;
  int*   pos_of = (int*)p; p += (size_t)NS * 4;
  int*   ti     = (int*)p; p += (size_t)NS * 4;
  float* tw     = (float*)p; p += (size_t)NS * 4;
  int* cursors = (int*)p; p += 64;
  int* offs    = (int*)p; p += 64;
  unsigned short* Yg = Xg;  // alias: Xg dead after gemm1, Yg born in gemm2

  dim3 tb(32, 8);
  transpose_cvt<<<dim3(F_ / 32, D_ / 32, E_), tb, 0, stream>>>(w1, w1t, D_, F_);
  transpose_cvt<<<dim3(D_ / 32, F_ / 32, E_), tb, 0, stream>>>(w2, w2t, F_, D_);
  router_k<<<NT / 4, 256, 0, stream>>>(x, gw, gb, ti, tw);
  count_prefix_k<<<1, 256, 0, stream>>>(ti, offs, cursors);
  fill_k<<<(CAP + 255) / 256, 256, 0, stream>>>(idx);
  scatter_k<<<NS / 256, 256, 0, stream>>>(ti, tw, cursors, idx, pos_of);
  gather_k<<<CAP, 256, 0, stream>>>(x, idx, Xg);
  gemm_k<D_, F_, true><<<dim3(F_ / 128, CAP / 128), 256, 0, stream>>>(Xg, w1t, b1, H, offs);
  gemm_k<F_, D_, false><<<dim3(D_ / 128, CAP / 128), 256, 0, stream>>>(H, w2t, b2, Yg, offs);
  combine_k<<<NT, 256, 0, stream>>>(Yg, pos_of, tw, out);
}